// Round 2
// baseline (1091.333 us; speedup 1.0000x reference)
//
#include <hip/hip_runtime.h>
#include <hip/hip_bf16.h>

typedef __hip_bfloat16 bf16;

static constexpr int HN  = 4;     // heads
static constexpr int NB  = 8;     // batch
static constexpr int SEQ = 1024;  // nodes
static constexpr int EMB = 128;
static constexpr int KD  = 32;
static constexpr int FFH = 512;
static constexpr int ROWS = NB * SEQ;       // 8192
static constexpr float EPS = 1e-5f;

__device__ __forceinline__ float b2f(bf16 x){ return __bfloat162float(x); }
__device__ __forceinline__ bf16  f2b(float x){ return __float2bfloat16(x); }

// dtype-dispatched load: flag==1 -> buffer is float32, else bf16
__device__ __forceinline__ float ldx(const void* p, size_t i, int f32){
    return f32 ? ((const float*)p)[i] : b2f(((const bf16*)p)[i]);
}

// unpack 8 bf16 (one uint4) -> 8 f32
__device__ __forceinline__ void bf16x8_to_f32(uint4 v, float* o){
    o[0]=__uint_as_float(v.x<<16); o[1]=__uint_as_float(v.x&0xffff0000u);
    o[2]=__uint_as_float(v.y<<16); o[3]=__uint_as_float(v.y&0xffff0000u);
    o[4]=__uint_as_float(v.z<<16); o[5]=__uint_as_float(v.z&0xffff0000u);
    o[6]=__uint_as_float(v.w<<16); o[7]=__uint_as_float(v.w&0xffff0000u);
}

// ---------------- K0: per-input dtype detector ----------------------------
__device__ __forceinline__ float probe_max(const unsigned int* w, int nwords, int t){
    float mx = 0.f;
    for (int i = t; i < nwords; i += 256) {
        float v = fabsf(__uint_as_float(w[i] << 16));
        if (!(v <= 1e4f)) v = 1e30f;
        mx = fmaxf(mx, v);
    }
    return mx;
}

// flags: 0=input1 1=input2 2=Wq 3=Wk 4=Wv 5=Wo 6=tinyMLP 7=Wff1 8=Wff2
__global__ __launch_bounds__(256) void detect_kernel(
    const unsigned int* in1, const unsigned int* in2,
    const unsigned int* wq,  const unsigned int* wk, const unsigned int* wv,
    const unsigned int* wo,  const unsigned int* ws1, const unsigned int* bs1,
    const unsigned int* ws2, const unsigned int* bs2,
    const unsigned int* wf1, const unsigned int* wf2, int* __restrict__ flags)
{
    __shared__ float red[4];
    const int b = blockIdx.x, t = threadIdx.x;
    float mx = 0.f;
    if      (b == 0) mx = probe_max(in1, 4096, t);
    else if (b == 1) mx = probe_max(in2, 4096, t);
    else if (b == 2) mx = probe_max(wq, 4096, t);
    else if (b == 3) mx = probe_max(wk, 4096, t);
    else if (b == 4) mx = probe_max(wv, 4096, t);
    else if (b == 5) mx = probe_max(wo, 4096, t);
    else if (b == 6) {
        mx = fmaxf(probe_max(ws1, 32, t), probe_max(bs1, 4, t));
        mx = fmaxf(mx, fmaxf(probe_max(ws2, 16, t), probe_max(bs2, 2, t)));
    }
    else if (b == 7) mx = probe_max(wf1, 4096, t);
    else             mx = probe_max(wf2, 4096, t);

    #pragma unroll
    for (int off = 32; off >= 1; off >>= 1) mx = fmaxf(mx, __shfl_xor(mx, off));
    if ((t & 63) == 0) red[t >> 6] = mx;
    __syncthreads();
    if (t == 0) {
        mx = fmaxf(fmaxf(red[0], red[1]), fmaxf(red[2], red[3]));
        flags[b] = (mx > 1e4f) ? 1 : 0;
    }
}

// ---------------- K0b: resolve dtypes + transpose weights ONCE ------------
// h32[8192][128] f32; Wt[mat][h][k][e]; Wot[e][hk]; W1t[f][e]; W2t[e][f];
// mlp32: w1t[j][i] (64) | b1 (8) | w2[j][c] (32) | b2 (4)  = 108 floats
__global__ __launch_bounds__(256) void convert_kernel(
    const void* in1, const void* Wq, const void* Wk, const void* Wv, const void* Wo,
    const void* Ws1, const void* bs1, const void* Ws2, const void* bs2,
    const void* Wf1, const void* Wf2,
    float* __restrict__ h32, float* __restrict__ Wt, float* __restrict__ Wot,
    float* __restrict__ W1t, float* __restrict__ W2t, float* __restrict__ mlp32,
    const int* __restrict__ flags)
{
    int gid = blockIdx.x * 256 + threadIdx.x;
    if (gid < 262144) {                         // input1 -> f32, 4 elems/thread
        if (flags[0]) {
            ((float4*)h32)[gid] = ((const float4*)in1)[gid];
        } else {
            const bf16* p = (const bf16*)in1 + (size_t)gid * 4;
            h32[gid*4+0] = b2f(p[0]); h32[gid*4+1] = b2f(p[1]);
            h32[gid*4+2] = b2f(p[2]); h32[gid*4+3] = b2f(p[3]);
        }
        return;
    }
    int r = gid - 262144;
    if (r < 49152) {                            // Wt[mat][h][k][e] = W[h][e][k]
        int mat = r >> 14, q = r & 16383;
        int h = q >> 12, k = (q >> 7) & 31, e = q & 127;
        const void* W = (mat == 0) ? Wq : (mat == 1) ? Wk : Wv;
        Wt[r] = ldx(W, (size_t)(h*EMB + e)*KD + k, flags[2+mat]);
        return;
    }
    r -= 49152;
    if (r < 16384) {                            // Wot[e][hk] = Wo[hk][e]
        int e = r >> 7, hk = r & 127;
        Wot[r] = ldx(Wo, (size_t)hk*EMB + e, flags[5]);
        return;
    }
    r -= 16384;
    if (r < 65536) {                            // W1t[f][e] = Wf1[e][f]
        int f = r >> 7, e = r & 127;
        W1t[r] = ldx(Wf1, (size_t)e*FFH + f, flags[7]);
        return;
    }
    r -= 65536;
    if (r < 65536) {                            // W2t[e][f] = Wf2[f][e]
        int e = r >> 9, f = r & 511;
        W2t[r] = ldx(Wf2, (size_t)f*EMB + e, flags[8]);
        return;
    }
    r -= 65536;
    if (r < 108) {
        const int fm = flags[6];
        float v;
        if (r < 64)       { int j = r >> 3, i = r & 7; v = ldx(Ws1, i*8 + j, fm); }
        else if (r < 72)  v = ldx(bs1, r - 64, fm);
        else if (r < 104) v = ldx(Ws2, r - 72, fm);    // w2[j][c] row-major kept
        else              v = ldx(bs2, r - 104, fm);
        mlp32[r] = v;
    }
}

// ---------------- K1: QKV projection (all f32 in, bf16 out) ---------------
// Q,K,V all [h][row][k] bf16
__global__ __launch_bounds__(256) void qkv_kernel(
    const float* __restrict__ h32, const float* __restrict__ Wt,
    bf16* __restrict__ Q, bf16* __restrict__ K, bf16* __restrict__ V)
{
    int gid = blockIdx.x * 256 + threadIdx.x;   // 3 * 2^20
    int mat = gid >> 20;
    int q   = gid & 1048575;
    int hh  = q >> 18;
    int row = (q >> 5) & 8191;
    int k   = q & 31;
    const float4* hv = reinterpret_cast<const float4*>(h32 + (size_t)row * EMB);
    const float4* wv = reinterpret_cast<const float4*>(Wt + ((size_t)(mat*HN + hh)*KD + k) * EMB);
    float acc = 0.f;
    #pragma unroll 8
    for (int i = 0; i < 32; i++) {
        float4 a = hv[i], w = wv[i];
        acc += a.x*w.x + a.y*w.y + a.z*w.z + a.w*w.w;
    }
    bf16* out = (mat == 0) ? Q : (mat == 1) ? K : V;
    out[((size_t)hh*ROWS + row)*KD + k] = f2b(acc);
}

// ---------------- K2: fused attention, 2 rows per block -------------------
// Phase A: in2 prefetch + scores(QK^T) -> tiny MLP -> z logits (LDS)
// Phase B: per-wave softmax, p kept in registers
// Phase C: PV from registers, cross-lane reduce via LDS (overlaid on z)
__global__ __launch_bounds__(256) void attn_kernel(
    const bf16* __restrict__ Q, const bf16* __restrict__ K, const bf16* __restrict__ V,
    const void* __restrict__ in2, const float* __restrict__ mlp,
    float* __restrict__ heads, const int* __restrict__ flags)
{
    __shared__ float zred[4*32*68];     // 8704 f: z[2][4][1024] (A/B) ∪ red[4][32][68] (C)
    __shared__ float qrow[2][HN][KD];
    __shared__ float wm[108];
    __shared__ float invs[2][HN];

    const int t    = threadIdx.x;
    const int row0 = blockIdx.x * 2;
    const int b    = row0 >> 10;
    const int n0   = row0 & (SEQ - 1);
    const int mm0  = t * 4;
    const int f2   = flags[1];

    { int r = t >> 7, h = (t >> 5) & 3, k = t & 31;
      qrow[r][h][k] = b2f(Q[((size_t)h*ROWS + row0 + r)*KD + k]); }
    if (t < 108) wm[t] = mlp[t];

    // ---- in2 prefetch FIRST: HBM latency hides under the QK^T compute ----
    float xx[2][4][8];                  // [row][m][channel]
    #pragma unroll
    for (int r = 0; r < 2; r++) {
        #pragma unroll
        for (int hh = 0; hh < HN; hh++) {
            size_t base = ((size_t)(hh*NB + b)*SEQ + (n0 + r))*SEQ + mm0;
            if (f2) {
                float4 v = *reinterpret_cast<const float4*>((const float*)in2 + base);
                xx[r][0][4+hh]=v.x; xx[r][1][4+hh]=v.y; xx[r][2][4+hh]=v.z; xx[r][3][4+hh]=v.w;
            } else {
                const bf16* p = (const bf16*)in2 + base;
                xx[r][0][4+hh]=b2f(p[0]); xx[r][1][4+hh]=b2f(p[1]);
                xx[r][2][4+hh]=b2f(p[2]); xx[r][3][4+hh]=b2f(p[3]);
            }
        }
    }
    __syncthreads();

    // ---- Phase A: each thread owns 4 contiguous m positions, both rows ----
    #pragma unroll
    for (int hh = 0; hh < HN; hh++) {
        float q0[KD], q1[KD];
        #pragma unroll
        for (int i = 0; i < 8; i++) {
            float4 a = *reinterpret_cast<const float4*>(&qrow[0][hh][i*4]);
            float4 c = *reinterpret_cast<const float4*>(&qrow[1][hh][i*4]);
            q0[4*i+0]=a.x; q0[4*i+1]=a.y; q0[4*i+2]=a.z; q0[4*i+3]=a.w;
            q1[4*i+0]=c.x; q1[4*i+1]=c.y; q1[4*i+2]=c.z; q1[4*i+3]=c.w;
        }
        const bf16* kp = K + ((size_t)(hh*NB + b)*SEQ + mm0) * KD;
        #pragma unroll
        for (int m = 0; m < 4; m++) {
            const uint4* kv = reinterpret_cast<const uint4*>(kp + m*KD);
            float kr[KD];
            bf16x8_to_f32(kv[0], kr+0);  bf16x8_to_f32(kv[1], kr+8);
            bf16x8_to_f32(kv[2], kr+16); bf16x8_to_f32(kv[3], kr+24);
            float a0 = 0.f, a1 = 0.f;
            #pragma unroll
            for (int k = 0; k < KD; k++) { a0 += q0[k]*kr[k]; a1 += q1[k]*kr[k]; }
            xx[0][m][hh] = a0; xx[1][m][hh] = a1;
        }
    }
    // tiny MLP, weights streamed j-wise so LDS reads are ~32, not ~800
    float zc[2][4][4];
    #pragma unroll
    for (int r = 0; r < 2; r++)
        #pragma unroll
        for (int m = 0; m < 4; m++)
            #pragma unroll
            for (int c = 0; c < 4; c++) zc[r][m][c] = wm[104 + c];
    #pragma unroll
    for (int j = 0; j < 8; j++) {
        float4 wa = *reinterpret_cast<const float4*>(&wm[j*8]);
        float4 wb = *reinterpret_cast<const float4*>(&wm[j*8+4]);
        float w1j[8] = {wa.x,wa.y,wa.z,wa.w, wb.x,wb.y,wb.z,wb.w};
        float b1j = wm[64 + j];
        float4 w2v = *reinterpret_cast<const float4*>(&wm[72 + j*4]);
        #pragma unroll
        for (int r = 0; r < 2; r++) {
            #pragma unroll
            for (int m = 0; m < 4; m++) {
                float y = b1j;
                #pragma unroll
                for (int i = 0; i < 8; i++) y += xx[r][m][i] * w1j[i];
                y = fmaxf(y, 0.f);
                zc[r][m][0] += y * w2v.x; zc[r][m][1] += y * w2v.y;
                zc[r][m][2] += y * w2v.z; zc[r][m][3] += y * w2v.w;
            }
        }
    }
    #pragma unroll
    for (int r = 0; r < 2; r++)
        #pragma unroll
        for (int c = 0; c < 4; c++)
            *reinterpret_cast<float4*>(&zred[((r*4 + c) << 10) + mm0]) =
                make_float4(zc[r][0][c], zc[r][1][c], zc[r][2][c], zc[r][3][c]);
    __syncthreads();

    // ---- Phase B: wave w = attention head w; p kept in registers ----
    const int wv = t >> 6, l = t & 63;
    float p0[16], p1[16];
    {
        const float* zb0 = &zred[((0*4 + wv) << 10) + l*16];
        const float* zb1 = &zred[((1*4 + wv) << 10) + l*16];
        #pragma unroll
        for (int i = 0; i < 4; i++) {
            float4 a = *reinterpret_cast<const float4*>(zb0 + i*4);
            float4 c = *reinterpret_cast<const float4*>(zb1 + i*4);
            p0[4*i+0]=a.x; p0[4*i+1]=a.y; p0[4*i+2]=a.z; p0[4*i+3]=a.w;
            p1[4*i+0]=c.x; p1[4*i+1]=c.y; p1[4*i+2]=c.z; p1[4*i+3]=c.w;
        }
        float mx0 = -1e30f, mx1 = -1e30f;
        #pragma unroll
        for (int i = 0; i < 16; i++) { mx0 = fmaxf(mx0, p0[i]); mx1 = fmaxf(mx1, p1[i]); }
        #pragma unroll
        for (int off = 32; off >= 1; off >>= 1) {
            mx0 = fmaxf(mx0, __shfl_xor(mx0, off));
            mx1 = fmaxf(mx1, __shfl_xor(mx1, off));
        }
        float s0 = 0.f, s1 = 0.f;
        #pragma unroll
        for (int i = 0; i < 16; i++) {
            p0[i] = __expf(p0[i] - mx0); s0 += p0[i];
            p1[i] = __expf(p1[i] - mx1); s1 += p1[i];
        }
        #pragma unroll
        for (int off = 32; off >= 1; off >>= 1) { s0 += __shfl_xor(s0, off); s1 += __shfl_xor(s1, off); }
        if (l == 0) { invs[0][wv] = 1.f / s0; invs[1][wv] = 1.f / s1; }
    }
    __syncthreads();                     // all z reads done -> zred reusable

    // ---- Phase C: PV; lane l owns m in [l*16, l*16+16) ----
    float o0[KD], o1[KD];
    #pragma unroll
    for (int k = 0; k < KD; k++) { o0[k] = 0.f; o1[k] = 0.f; }
    const bf16* vp = V + ((size_t)(wv*NB + b)*SEQ + l*16) * KD;
    #pragma unroll
    for (int j = 0; j < 16; j++) {
        const uint4* vvp = reinterpret_cast<const uint4*>(vp + j*KD);
        float vr[KD];
        bf16x8_to_f32(vvp[0], vr+0);  bf16x8_to_f32(vvp[1], vr+8);
        bf16x8_to_f32(vvp[2], vr+16); bf16x8_to_f32(vvp[3], vr+24);
        #pragma unroll
        for (int k = 0; k < KD; k++) { o0[k] += p0[j]*vr[k]; o1[k] += p1[j]*vr[k]; }
    }
    #pragma unroll
    for (int k = 0; k < KD; k++) { o0[k] += __shfl_xor(o0[k], 32); o1[k] += __shfl_xor(o1[k], 32); }
    if (l < 32) {
        float* rr = &zred[(wv*32 + l)*68];
        #pragma unroll
        for (int i = 0; i < 8; i++) {
            *reinterpret_cast<float4*>(rr + i*4)      = make_float4(o0[4*i], o0[4*i+1], o0[4*i+2], o0[4*i+3]);
            *reinterpret_cast<float4*>(rr + 32 + i*4) = make_float4(o1[4*i], o1[4*i+1], o1[4*i+2], o1[4*i+3]);
        }
    }
    __syncthreads();
    {
        int r = t >> 7, h = (t >> 5) & 3, k = t & 31;
        float acc = 0.f;
        #pragma unroll 8
        for (int l2 = 0; l2 < 32; l2++) acc += zred[(h*32 + l2)*68 + r*32 + k];
        heads[((size_t)h*ROWS + row0 + r)*KD + k] = acc * invs[r][h];
    }
}

// ---------------- K3: out-projection + residual + LN partials -------------
__global__ __launch_bounds__(256) void outproj_kernel(
    const float* __restrict__ heads, const float* __restrict__ Wot,
    const float* __restrict__ h32, float* __restrict__ outp,
    float* __restrict__ ps, float* __restrict__ pq)
{
    const int gid = blockIdx.x * 256 + threadIdx.x;
    const int row = gid >> 7, e = gid & 127;
    float acc = h32[gid];
    #pragma unroll
    for (int h = 0; h < HN; h++) {
        const float4* hp = reinterpret_cast<const float4*>(heads + ((size_t)h*ROWS + row)*KD);
        const float4* wp = reinterpret_cast<const float4*>(Wot + (size_t)e*EMB + h*KD);
        #pragma unroll
        for (int i = 0; i < 8; i++) {
            float4 a = hp[i], w = wp[i];
            acc += a.x*w.x + a.y*w.y + a.z*w.z + a.w*w.w;
        }
    }
    outp[gid] = acc;
    float s = acc, q = acc * acc;
    #pragma unroll
    for (int off = 32; off >= 1; off >>= 1) { s += __shfl_xor(s, off); q += __shfl_xor(q, off); }
    __shared__ float ls[4], lq[4];
    if ((threadIdx.x & 63) == 0) { ls[threadIdx.x >> 6] = s; lq[threadIdx.x >> 6] = q; }
    __syncthreads();
    if (threadIdx.x == 0) {
        ps[blockIdx.x] = ls[0] + ls[1] + ls[2] + ls[3];
        pq[blockIdx.x] = lq[0] + lq[1] + lq[2] + lq[3];
    }
}

// ---------------- K4/K7: finalize LN stats per batch ----------------------
__global__ __launch_bounds__(256) void stats_kernel(
    const float* __restrict__ ps, const float* __restrict__ pq,
    float* __restrict__ stats, int per_b, float M)
{
    int b = blockIdx.x, t = threadIdx.x;
    float s = 0.f, q = 0.f;
    for (int i = t; i < per_b; i += 256) { s += ps[b * per_b + i]; q += pq[b * per_b + i]; }
    #pragma unroll
    for (int off = 32; off >= 1; off >>= 1) { s += __shfl_xor(s, off); q += __shfl_xor(q, off); }
    __shared__ float ls[4], lq[4];
    if ((t & 63) == 0) { ls[t >> 6] = s; lq[t >> 6] = q; }
    __syncthreads();
    if (t == 0) {
        s = ls[0] + ls[1] + ls[2] + ls[3];
        q = lq[0] + lq[1] + lq[2] + lq[3];
        float mean = s / M;
        float var = (q - s * s / M) / (M - 1.0f);
        stats[2 * b] = mean;
        stats[2 * b + 1] = 1.0f / sqrtf(var + EPS);
    }
}

// ---------------- K6: LN1-apply + FF1+relu+FF2+residual + LN partials -----
// 4 rows per block; weights pre-transposed so all global loads are b128
__global__ __launch_bounds__(256) void ff_kernel(
    const float* __restrict__ outp, const float* __restrict__ stats,
    const float* __restrict__ W1t, const float* __restrict__ W2t,
    float* __restrict__ outp2, float* __restrict__ ps, float* __restrict__ pq)
{
    __shared__ float xr[4][EMB];
    __shared__ float hid[4][FFH];
    __shared__ float rs[4], rq[4];
    const int t = threadIdx.x;
    const int row0 = blockIdx.x * 4;
    const int b = row0 >> 10;
    const float mean = stats[2*b], rstd = stats[2*b+1];

    #pragma unroll
    for (int i = 0; i < 2; i++) {
        int idx = t + 256*i;
        xr[idx >> 7][idx & 127] = (outp[(size_t)row0*EMB + idx] - mean) * rstd;
    }
    __syncthreads();

    {   // FF1: thread t owns hidden f = {t, t+256} for all 4 rows
        const float4* w0 = reinterpret_cast<const float4*>(W1t + (size_t)t * EMB);
        const float4* w1 = reinterpret_cast<const float4*>(W1t + (size_t)(t + 256) * EMB);
        float a[2][4] = {};
        #pragma unroll 8
        for (int i = 0; i < 32; i++) {
            float4 wa = w0[i], wb = w1[i];
            #pragma unroll
            for (int r = 0; r < 4; r++) {
                float4 x = *reinterpret_cast<const float4*>(&xr[r][i*4]);
                a[0][r] += wa.x*x.x + wa.y*x.y + wa.z*x.z + wa.w*x.w;
                a[1][r] += wb.x*x.x + wb.y*x.y + wb.z*x.z + wb.w*x.w;
            }
        }
        #pragma unroll
        for (int r = 0; r < 4; r++) {
            hid[r][t]       = fmaxf(a[0][r], 0.f);
            hid[r][t + 256] = fmaxf(a[1][r], 0.f);
        }
    }
    __syncthreads();

    // FF2: thread pair (e, half) splits the f-sum; all 4 rows share W row
    const int e = t >> 1, half = t & 1;
    float acc[4] = {};
    {
        const float4* wvp = reinterpret_cast<const float4*>(W2t + (size_t)e*FFH + half*256);
        #pragma unroll 8
        for (int i = 0; i < 64; i++) {
            float4 w = wvp[i];
            int fb = half*256 + i*4;
            #pragma unroll
            for (int r = 0; r < 4; r++) {
                float4 h4 = *reinterpret_cast<const float4*>(&hid[r][fb]);
                acc[r] += w.x*h4.x + w.y*h4.y + w.z*h4.z + w.w*h4.w;
            }
        }
    }
    #pragma unroll
    for (int r = 0; r < 4; r++) acc[r] += __shfl_xor(acc[r], 1);
    float s = 0.f, q = 0.f;
    if (half == 0) {
        #pragma unroll
        for (int r = 0; r < 4; r++) {
            float v = acc[r] + xr[r][e];
            outp2[(size_t)(row0 + r)*EMB + e] = v;
            s += v; q += v * v;
        }
    }
    #pragma unroll
    for (int off = 32; off >= 1; off >>= 1) { s += __shfl_xor(s, off); q += __shfl_xor(q, off); }
    if ((t & 63) == 0) { rs[t >> 6] = s; rq[t >> 6] = q; }
    __syncthreads();
    if (t == 0) {
        ps[blockIdx.x] = rs[0] + rs[1] + rs[2] + rs[3];
        pq[blockIdx.x] = rq[0] + rq[1] + rq[2] + rq[3];
    }
}

// ---------------- K8: apply LN2 -> float out ------------------------------
__global__ __launch_bounds__(256) void final_kernel(
    const float* __restrict__ in, const float* __restrict__ stats, float* __restrict__ out)
{
    int gid = blockIdx.x * 256 + threadIdx.x;
    int b = gid >> 17;
    out[gid] = (in[gid] - stats[2 * b]) * stats[2 * b + 1];
}

// ---------------- K9: input2 passthrough -> float out ---------------------
__global__ __launch_bounds__(256) void copy2_kernel(
    const void* __restrict__ in, uint4* __restrict__ out, const int* __restrict__ flags)
{
    const int f_2 = flags[1];
    size_t gid = (size_t)blockIdx.x * 256 + threadIdx.x;
    if (f_2) {
        out[gid] = ((const uint4*)in)[gid];
    } else {
        const bf16* p = (const bf16*)in + gid * 4;
        float4 v = { b2f(p[0]), b2f(p[1]), b2f(p[2]), b2f(p[3]) };
        out[gid] = *(const uint4*)&v;
    }
}

extern "C" void kernel_launch(void* const* d_in, const int* in_sizes, int n_in,
                              void* d_out, int out_size, void* d_ws, size_t ws_size,
                              hipStream_t stream)
{
    const void* input1 = d_in[0];
    const void* input2 = d_in[1];
    const void* Wq  = d_in[2];
    const void* Wk  = d_in[3];
    const void* Wv  = d_in[4];
    const void* Wo  = d_in[5];
    const void* Ws1 = d_in[6];
    const void* bs1 = d_in[7];
    const void* Ws2 = d_in[8];
    const void* bs2 = d_in[9];
    const void* Wf1 = d_in[10];
    const void* Wf2 = d_in[11];

    float* out1 = (float*)d_out;                       // [ROWS*EMB] f32
    float* out2 = (float*)d_out + (size_t)ROWS * EMB;  // input2 passthrough (written LAST)

    // Scratch inside the out2 region (~23 MiB used of 128 MiB); all consumers
    // finish before copy2 overwrites it.
    char* sb = (char*)out2;
    bf16*  Q     = (bf16*)(sb);                        // 2 MB
    bf16*  Kb    = (bf16*)(sb + (2u  << 20));          // 2 MB
    bf16*  V     = (bf16*)(sb + (4u  << 20));          // 2 MB
    float* heads = (float*)(sb + (6u  << 20));         // 4 MB
    float* outp  = (float*)(sb + (10u << 20));         // 4 MB
    float* outp2 = (float*)(sb + (14u << 20));         // 4 MB
    float* h32   = (float*)(sb + (18u << 20));         // 4 MB
    float* Wt    = (float*)(sb + (22u << 20));                 // 192 KB
    float* Wot   = (float*)(sb + (22u << 20) + 0x30000);       // 64 KB
    float* W1t   = (float*)(sb + (22u << 20) + 0x40000);       // 256 KB
    float* W2t   = (float*)(sb + (22u << 20) + 0x80000);       // 256 KB
    float* mlp32 = (float*)(sb + (22u << 20) + 0xC0000);       // 432 B
    float* ps    = (float*)(sb + (22u << 20) + 0xC1000);       // 16 KB
    float* pq    = (float*)(sb + (22u << 20) + 0xC5000);       // 16 KB
    float* stats = (float*)(sb + (22u << 20) + 0xC9000);
    float* stats2= (float*)(sb + (22u << 20) + 0xC9100);
    int*   flags = (int*)  (sb + (22u << 20) + 0xC9200);

    const float M = (float)(SEQ * EMB);                // 131072 per batch

    hipLaunchKernelGGL(detect_kernel, dim3(9), dim3(256), 0, stream,
                       (const unsigned int*)input1, (const unsigned int*)input2,
                       (const unsigned int*)Wq, (const unsigned int*)Wk,
                       (const unsigned int*)Wv, (const unsigned int*)Wo,
                       (const unsigned int*)Ws1, (const unsigned int*)bs1,
                       (const unsigned int*)Ws2, (const unsigned int*)bs2,
                       (const unsigned int*)Wf1, (const unsigned int*)Wf2, flags);
    hipLaunchKernelGGL(convert_kernel, dim3(1793), dim3(256), 0, stream,
                       input1, Wq, Wk, Wv, Wo, Ws1, bs1, Ws2, bs2, Wf1, Wf2,
                       h32, Wt, Wot, W1t, W2t, mlp32, flags);
    hipLaunchKernelGGL(qkv_kernel, dim3(3 * HN * ROWS * KD / 256), dim3(256), 0, stream,
                       h32, Wt, Q, Kb, V);
    hipLaunchKernelGGL(attn_kernel, dim3(ROWS / 2), dim3(256), 0, stream,
                       Q, Kb, V, input2, mlp32, heads, flags);
    hipLaunchKernelGGL(outproj_kernel, dim3(ROWS * EMB / 256), dim3(256), 0, stream,
                       heads, Wot, h32, outp, ps, pq);
    hipLaunchKernelGGL(stats_kernel, dim3(NB), dim3(256), 0, stream,
                       ps, pq, stats, 512, M);
    hipLaunchKernelGGL(ff_kernel, dim3(ROWS / 4), dim3(256), 0, stream,
                       outp, stats, W1t, W2t, outp2, ps, pq);
    hipLaunchKernelGGL(stats_kernel, dim3(NB), dim3(256), 0, stream,
                       ps, pq, stats2, 256, M);
    hipLaunchKernelGGL(final_kernel, dim3(ROWS * EMB / 256), dim3(256), 0, stream,
                       outp2, stats2, out1);
    hipLaunchKernelGGL(copy2_kernel, dim3(ROWS * SEQ * HN / 4 / 256), dim3(256), 0, stream,
                       input2, (uint4*)out2, flags);
}

// Round 4
// 982.124 us; speedup vs baseline: 1.1112x; 1.1112x over previous
//
#include <hip/hip_runtime.h>
#include <hip/hip_bf16.h>

typedef __hip_bfloat16 bf16;

static constexpr int HN  = 4;     // heads
static constexpr int NB  = 8;     // batch
static constexpr int SEQ = 1024;  // nodes
static constexpr int EMB = 128;
static constexpr int KD  = 32;
static constexpr int FFH = 512;
static constexpr int ROWS = NB * SEQ;       // 8192
static constexpr float EPS = 1e-5f;

__device__ __forceinline__ float b2f(bf16 x){ return __bfloat162float(x); }

// dtype-dispatched load: flag==1 -> buffer is float32, else bf16
__device__ __forceinline__ float ldx(const void* p, size_t i, int f32){
    return f32 ? ((const float*)p)[i] : b2f(((const bf16*)p)[i]);
}

// ---------------- K0: per-input dtype detector ----------------------------
__device__ __forceinline__ float probe_max(const unsigned int* w, int nwords, int t){
    float mx = 0.f;
    for (int i = t; i < nwords; i += 256) {
        float v = fabsf(__uint_as_float(w[i] << 16));
        if (!(v <= 1e4f)) v = 1e30f;
        mx = fmaxf(mx, v);
    }
    return mx;
}

// flags: 0=input1 1=input2 2=Wq 3=Wk 4=Wv 5=Wo 6=tinyMLP 7=Wff1 8=Wff2
__global__ __launch_bounds__(256) void detect_kernel(
    const unsigned int* in1, const unsigned int* in2,
    const unsigned int* wq,  const unsigned int* wk, const unsigned int* wv,
    const unsigned int* wo,  const unsigned int* ws1, const unsigned int* bs1,
    const unsigned int* ws2, const unsigned int* bs2,
    const unsigned int* wf1, const unsigned int* wf2, int* __restrict__ flags)
{
    __shared__ float red[4];
    const int b = blockIdx.x, t = threadIdx.x;
    float mx = 0.f;
    if      (b == 0) mx = probe_max(in1, 4096, t);
    else if (b == 1) mx = probe_max(in2, 4096, t);
    else if (b == 2) mx = probe_max(wq, 4096, t);
    else if (b == 3) mx = probe_max(wk, 4096, t);
    else if (b == 4) mx = probe_max(wv, 4096, t);
    else if (b == 5) mx = probe_max(wo, 4096, t);
    else if (b == 6) {
        mx = fmaxf(probe_max(ws1, 32, t), probe_max(bs1, 4, t));
        mx = fmaxf(mx, fmaxf(probe_max(ws2, 16, t), probe_max(bs2, 2, t)));
    }
    else if (b == 7) mx = probe_max(wf1, 4096, t);
    else             mx = probe_max(wf2, 4096, t);

    #pragma unroll
    for (int off = 32; off >= 1; off >>= 1) mx = fmaxf(mx, __shfl_xor(mx, off));
    if ((t & 63) == 0) red[t >> 6] = mx;
    __syncthreads();
    if (t == 0) {
        mx = fmaxf(fmaxf(red[0], red[1]), fmaxf(red[2], red[3]));
        flags[b] = (mx > 1e4f) ? 1 : 0;
    }
}

// ---------------- K0b: resolve dtypes + transpose weights ONCE ------------
// h32[8192][128] f32; Wt[mat][h][k][e]; Wot[e][hk]; W1t[f][e]; W2t[e][f];
// mlp32: w1t[j][i] (64) | b1 (8) | w2[j][c] (32) | b2 (4)  = 108 floats
__global__ __launch_bounds__(256) void convert_kernel(
    const void* in1, const void* Wq, const void* Wk, const void* Wv, const void* Wo,
    const void* Ws1, const void* bs1, const void* Ws2, const void* bs2,
    const void* Wf1, const void* Wf2,
    float* __restrict__ h32, float* __restrict__ Wt, float* __restrict__ Wot,
    float* __restrict__ W1t, float* __restrict__ W2t, float* __restrict__ mlp32,
    const int* __restrict__ flags)
{
    int gid = blockIdx.x * 256 + threadIdx.x;
    if (gid < 262144) {                         // input1 -> f32, 4 elems/thread
        if (flags[0]) {
            ((float4*)h32)[gid] = ((const float4*)in1)[gid];
        } else {
            const bf16* p = (const bf16*)in1 + (size_t)gid * 4;
            h32[gid*4+0] = b2f(p[0]); h32[gid*4+1] = b2f(p[1]);
            h32[gid*4+2] = b2f(p[2]); h32[gid*4+3] = b2f(p[3]);
        }
        return;
    }
    int r = gid - 262144;
    if (r < 49152) {                            // Wt[mat][h][k][e] = W[h][e][k]
        int mat = r >> 14, q = r & 16383;
        int h = q >> 12, k = (q >> 7) & 31, e = q & 127;
        const void* W = (mat == 0) ? Wq : (mat == 1) ? Wk : Wv;
        Wt[r] = ldx(W, (size_t)(h*EMB + e)*KD + k, flags[2+mat]);
        return;
    }
    r -= 49152;
    if (r < 16384) {                            // Wot[e][hk] = Wo[hk][e]
        int e = r >> 7, hk = r & 127;
        Wot[r] = ldx(Wo, (size_t)hk*EMB + e, flags[5]);
        return;
    }
    r -= 16384;
    if (r < 65536) {                            // W1t[f][e] = Wf1[e][f]
        int f = r >> 7, e = r & 127;
        W1t[r] = ldx(Wf1, (size_t)e*FFH + f, flags[7]);
        return;
    }
    r -= 65536;
    if (r < 65536) {                            // W2t[e][f] = Wf2[f][e]
        int e = r >> 9, f = r & 511;
        W2t[r] = ldx(Wf2, (size_t)f*EMB + e, flags[8]);
        return;
    }
    r -= 65536;
    if (r < 108) {
        const int fm = flags[6];
        float v;
        if (r < 64)       { int j = r >> 3, i = r & 7; v = ldx(Ws1, i*8 + j, fm); }
        else if (r < 72)  v = ldx(bs1, r - 64, fm);
        else if (r < 104) v = ldx(Ws2, r - 72, fm);    // w2[j][c] row-major kept
        else              v = ldx(bs2, r - 104, fm);
        mlp32[r] = v;
    }
}

// ---------------- K1: QKV projection, LDS-tiled GEMM ----------------------
// Outputs (all f32): Q32[h][row][k], Kt32[h][b][k][n], Vt32[h][b][k][n]
// Block: one (mat, head, 128-row tile). h-tile staged in LDS [row][132].
__global__ __launch_bounds__(256) void qkv_kernel(
    const float* __restrict__ h32, const float* __restrict__ Wt,
    float* __restrict__ Q32, float* __restrict__ Kt32, float* __restrict__ Vt32)
{
    __shared__ float hl[128 * 132];             // [row][e], pad 132 (16B aligned rows)
    const int t   = threadIdx.x;
    const int bid = blockIdx.x;
    const int mat = bid >> 8;                   // 768 = 3 * 4 * 64
    const int hh  = (bid >> 6) & 3;
    const int rt  = bid & 63;
    const int row0 = rt * 128;

    #pragma unroll
    for (int i = 0; i < 16; i++) {              // stage 128x128 f32, coalesced
        int idx = t + 256 * i;                  // 0..4095
        int r  = idx >> 5;
        int e4 = (idx & 31) * 4;
        float4 v = *reinterpret_cast<const float4*>(h32 + (size_t)(row0 + r) * EMB + e4);
        *reinterpret_cast<float4*>(&hl[r * 132 + e4]) = v;
    }
    __syncthreads();

    const int rq = t >> 3;                      // 0..31 (4-row group)
    const int kq = t & 7;                       // 0..7  (4-k group)
    const float* wbase = Wt + ((size_t)(mat * HN + hh) * KD + kq * 4) * EMB;
    float acc[4][4] = {};                       // [r][kk]
    #pragma unroll 4
    for (int eq = 0; eq < 32; eq++) {
        float4 a0 = *reinterpret_cast<const float4*>(&hl[(rq*4+0)*132 + eq*4]);
        float4 a1 = *reinterpret_cast<const float4*>(&hl[(rq*4+1)*132 + eq*4]);
        float4 a2 = *reinterpret_cast<const float4*>(&hl[(rq*4+2)*132 + eq*4]);
        float4 a3 = *reinterpret_cast<const float4*>(&hl[(rq*4+3)*132 + eq*4]);
        float4 w0 = *reinterpret_cast<const float4*>(wbase + 0*EMB + eq*4);
        float4 w1 = *reinterpret_cast<const float4*>(wbase + 1*EMB + eq*4);
        float4 w2 = *reinterpret_cast<const float4*>(wbase + 2*EMB + eq*4);
        float4 w3 = *reinterpret_cast<const float4*>(wbase + 3*EMB + eq*4);
        #pragma unroll
        for (int kk = 0; kk < 4; kk++) {
            float4 w = (kk==0)?w0:(kk==1)?w1:(kk==2)?w2:w3;
            acc[0][kk] += a0.x*w.x + a0.y*w.y + a0.z*w.z + a0.w*w.w;
            acc[1][kk] += a1.x*w.x + a1.y*w.y + a1.z*w.z + a1.w*w.w;
            acc[2][kk] += a2.x*w.x + a2.y*w.y + a2.z*w.z + a2.w*w.w;
            acc[3][kk] += a3.x*w.x + a3.y*w.y + a3.z*w.z + a3.w*w.w;
        }
    }

    if (mat == 0) {                             // Q32[h][row][k]
        #pragma unroll
        for (int r = 0; r < 4; r++) {
            float4 v = { acc[r][0], acc[r][1], acc[r][2], acc[r][3] };
            *reinterpret_cast<float4*>(Q32 + ((size_t)hh*ROWS + row0 + rq*4 + r)*KD + kq*4) = v;
        }
    } else {                                    // Kt/Vt [h][b][k][n]
        float* out = (mat == 1) ? Kt32 : Vt32;
        int bb = row0 >> 10;
        int n0 = (row0 & 1023) + rq * 4;
        #pragma unroll
        for (int kk = 0; kk < 4; kk++) {
            float4 v = { acc[0][kk], acc[1][kk], acc[2][kk], acc[3][kk] };
            *reinterpret_cast<float4*>(out + ((size_t)(hh*NB + bb)*KD + kq*4 + kk)*SEQ + n0) = v;
        }
    }
}

// ---------------- K2: fused attention, 2 rows per block -------------------
// Phase 1: wave w computes head-w scores -> LDS s[h*2+r][1024]
// Phase 2: per-thread tiny MLP in-place (s -> z), in2 from prefetched regs
// Phase 3: per-wave softmax, p in registers (lane l owns m in {4l+256i})
// Phase 4: PV from f32 Vt, cross-lane reduce via LDS (overlaid)
__global__ __launch_bounds__(256, 3) void attn_kernel(
    const float* __restrict__ Q32, const float* __restrict__ Kt32,
    const float* __restrict__ Vt32, const void* __restrict__ in2,
    const float* __restrict__ mlp, float* __restrict__ heads,
    const int* __restrict__ flags)
{
    __shared__ float sz[8704];          // s/z planes [8][1024] ∪ red[4][32][68]
    __shared__ float qld[HN][2][KD];    // 1 KB
    __shared__ float wm[108];
    __shared__ float invs[2][HN];

    const int t = threadIdx.x;
    // XCD swizzle: 4096 blocks, 8 XCDs -> each XCD owns one contiguous 512
    // chunk = exactly one batch b -> its K/V (1 MB) stays L2-resident.
    const int wg   = (blockIdx.x & 7) * 512 + (blockIdx.x >> 3);
    const int row0 = wg * 2;
    const int b    = row0 >> 10;
    const int n0   = row0 & (SEQ - 1);
    const int m0   = t * 4;
    const int f2   = flags[1];
    const int w    = t >> 6, l = t & 63;

    { int h = t >> 6, r = (t >> 5) & 1, k = t & 31;
      qld[h][r][k] = Q32[((size_t)h*ROWS + row0 + r)*KD + k]; }
    if (t < 108) wm[t] = mlp[t];

    // in2 prefetch (regs) - issued early, consumed in Phase 2
    float4 i2v[2][4];
    #pragma unroll
    for (int r = 0; r < 2; r++) {
        #pragma unroll
        for (int c = 0; c < 4; c++) {
            size_t base = ((size_t)(c*NB + b)*SEQ + (n0 + r))*SEQ + m0;
            if (f2) {
                i2v[r][c] = *reinterpret_cast<const float4*>((const float*)in2 + base);
            } else {
                const ushort* p = (const ushort*)in2 + base;
                ushort4 u = *reinterpret_cast<const ushort4*>(p);
                i2v[r][c] = make_float4(
                    __uint_as_float((unsigned)u.x << 16), __uint_as_float((unsigned)u.y << 16),
                    __uint_as_float((unsigned)u.z << 16), __uint_as_float((unsigned)u.w << 16));
            }
        }
    }
    __syncthreads();

    // ---- Phase 1: wave w = head w; both rows; f32 K, coalesced float2 ----
    {
        float q0[KD], q1[KD];
        const float4* qp0 = reinterpret_cast<const float4*>(&qld[w][0][0]);
        const float4* qp1 = reinterpret_cast<const float4*>(&qld[w][1][0]);
        #pragma unroll
        for (int i = 0; i < 8; i++) {
            float4 a = qp0[i], c = qp1[i];
            q0[4*i+0]=a.x; q0[4*i+1]=a.y; q0[4*i+2]=a.z; q0[4*i+3]=a.w;
            q1[4*i+0]=c.x; q1[4*i+1]=c.y; q1[4*i+2]=c.z; q1[4*i+3]=c.w;
        }
        const float* kb = Kt32 + ((size_t)(w*NB + b)*KD)*SEQ;
        #pragma unroll 2
        for (int mc = 0; mc < 8; mc++) {
            const int m = mc*128 + l*2;
            float a00=0.f, a01=0.f, a10=0.f, a11=0.f;
            #pragma unroll
            for (int k = 0; k < KD; k++) {
                float2 kv = *reinterpret_cast<const float2*>(kb + (size_t)k*SEQ + m);
                a00 += q0[k]*kv.x; a01 += q0[k]*kv.y;
                a10 += q1[k]*kv.x; a11 += q1[k]*kv.y;
            }
            *reinterpret_cast<float2*>(&sz[(w*2+0)*SEQ + m]) = make_float2(a00, a01);
            *reinterpret_cast<float2*>(&sz[(w*2+1)*SEQ + m]) = make_float2(a10, a11);
        }
    }
    __syncthreads();

    // ---- Phase 2: tiny MLP, in-place s->z (per-thread same m-window) ----
    {
        float xx[2][4][8];              // [row][m][channel]
        #pragma unroll
        for (int h = 0; h < HN; h++) {
            #pragma unroll
            for (int r = 0; r < 2; r++) {
                float4 s4 = *reinterpret_cast<const float4*>(&sz[(h*2+r)*SEQ + m0]);
                xx[r][0][h]=s4.x; xx[r][1][h]=s4.y; xx[r][2][h]=s4.z; xx[r][3][h]=s4.w;
            }
        }
        #pragma unroll
        for (int r = 0; r < 2; r++)
            #pragma unroll
            for (int c = 0; c < 4; c++) {
                float4 v = i2v[r][c];
                xx[r][0][4+c]=v.x; xx[r][1][4+c]=v.y; xx[r][2][4+c]=v.z; xx[r][3][4+c]=v.w;
            }
        float zc[2][4][4];
        #pragma unroll
        for (int r = 0; r < 2; r++)
            #pragma unroll
            for (int m = 0; m < 4; m++)
                #pragma unroll
                for (int c = 0; c < 4; c++) zc[r][m][c] = wm[104 + c];
        #pragma unroll
        for (int j = 0; j < 8; j++) {
            float4 wa = *reinterpret_cast<const float4*>(&wm[j*8]);
            float4 wb = *reinterpret_cast<const float4*>(&wm[j*8+4]);
            float w1j[8] = {wa.x,wa.y,wa.z,wa.w, wb.x,wb.y,wb.z,wb.w};
            float b1j = wm[64 + j];
            float4 w2v = *reinterpret_cast<const float4*>(&wm[72 + j*4]);
            #pragma unroll
            for (int r = 0; r < 2; r++) {
                #pragma unroll
                for (int m = 0; m < 4; m++) {
                    float y = b1j;
                    #pragma unroll
                    for (int i = 0; i < 8; i++) y += xx[r][m][i] * w1j[i];
                    y = fmaxf(y, 0.f);
                    zc[r][m][0] += y * w2v.x; zc[r][m][1] += y * w2v.y;
                    zc[r][m][2] += y * w2v.z; zc[r][m][3] += y * w2v.w;
                }
            }
        }
        #pragma unroll
        for (int r = 0; r < 2; r++)
            #pragma unroll
            for (int c = 0; c < 4; c++)
                *reinterpret_cast<float4*>(&sz[(r*4 + c)*SEQ + m0]) =
                    make_float4(zc[r][0][c], zc[r][1][c], zc[r][2][c], zc[r][3][c]);
    }
    __syncthreads();

    // ---- Phase 3: wave w = head w softmax; lane l owns m in {4l+256i} ----
    // 16B lane stride -> conflict-free LDS reads (was 64B stride = 32-way).
    float p0[16], p1[16];
    {
        #pragma unroll
        for (int i = 0; i < 4; i++) {
            float4 a = *reinterpret_cast<const float4*>(&sz[(0*4 + w)*SEQ + i*256 + l*4]);
            float4 c = *reinterpret_cast<const float4*>(&sz[(1*4 + w)*SEQ + i*256 + l*4]);
            p0[4*i+0]=a.x; p0[4*i+1]=a.y; p0[4*i+2]=a.z; p0[4*i+3]=a.w;
            p1[4*i+0]=c.x; p1[4*i+1]=c.y; p1[4*i+2]=c.z; p1[4*i+3]=c.w;
        }
        float mx0 = -1e30f, mx1 = -1e30f;
        #pragma unroll
        for (int i = 0; i < 16; i++) { mx0 = fmaxf(mx0, p0[i]); mx1 = fmaxf(mx1, p1[i]); }
        #pragma unroll
        for (int off = 32; off >= 1; off >>= 1) {
            mx0 = fmaxf(mx0, __shfl_xor(mx0, off));
            mx1 = fmaxf(mx1, __shfl_xor(mx1, off));
        }
        float s0 = 0.f, s1 = 0.f;
        #pragma unroll
        for (int i = 0; i < 16; i++) {
            p0[i] = __expf(p0[i] - mx0); s0 += p0[i];
            p1[i] = __expf(p1[i] - mx1); s1 += p1[i];
        }
        #pragma unroll
        for (int off = 32; off >= 1; off >>= 1) { s0 += __shfl_xor(s0, off); s1 += __shfl_xor(s1, off); }
        if (l == 0) { invs[0][w] = 1.f / s0; invs[1][w] = 1.f / s1; }
    }
    __syncthreads();                     // z consumed -> sz reusable as red

    // ---- Phase 4: PV from f32 Vt; lane l owns m = 4l + 256i ----
    {
        float o0[KD], o1[KD];
        const float* vb = Vt32 + ((size_t)(w*NB + b)*KD)*SEQ + l*4;
        #pragma unroll 4
        for (int k = 0; k < KD; k++) {
            const float* vk = vb + (size_t)k*SEQ;
            float4 v0 = *reinterpret_cast<const float4*>(vk + 0*256);
            float4 v1 = *reinterpret_cast<const float4*>(vk + 1*256);
            float4 v2 = *reinterpret_cast<const float4*>(vk + 2*256);
            float4 v3 = *reinterpret_cast<const float4*>(vk + 3*256);
            o0[k] = p0[ 0]*v0.x + p0[ 1]*v0.y + p0[ 2]*v0.z + p0[ 3]*v0.w
                  + p0[ 4]*v1.x + p0[ 5]*v1.y + p0[ 6]*v1.z + p0[ 7]*v1.w
                  + p0[ 8]*v2.x + p0[ 9]*v2.y + p0[10]*v2.z + p0[11]*v2.w
                  + p0[12]*v3.x + p0[13]*v3.y + p0[14]*v3.z + p0[15]*v3.w;
            o1[k] = p1[ 0]*v0.x + p1[ 1]*v0.y + p1[ 2]*v0.z + p1[ 3]*v0.w
                  + p1[ 4]*v1.x + p1[ 5]*v1.y + p1[ 6]*v1.z + p1[ 7]*v1.w
                  + p1[ 8]*v2.x + p1[ 9]*v2.y + p1[10]*v2.z + p1[11]*v2.w
                  + p1[12]*v3.x + p1[13]*v3.y + p1[14]*v3.z + p1[15]*v3.w;
        }
        #pragma unroll
        for (int k = 0; k < KD; k++) { o0[k] += __shfl_xor(o0[k], 32); o1[k] += __shfl_xor(o1[k], 32); }
        if (l < 32) {
            float* rr = &sz[(w*32 + l)*68];
            #pragma unroll
            for (int i = 0; i < 8; i++) {
                *reinterpret_cast<float4*>(rr + i*4)      = make_float4(o0[4*i], o0[4*i+1], o0[4*i+2], o0[4*i+3]);
                *reinterpret_cast<float4*>(rr + 32 + i*4) = make_float4(o1[4*i], o1[4*i+1], o1[4*i+2], o1[4*i+3]);
            }
        }
    }
    __syncthreads();
    {
        int r = t >> 7, h = (t >> 5) & 3, k = t & 31;
        float acc = 0.f;
        #pragma unroll 8
        for (int l2 = 0; l2 < 32; l2++) acc += sz[(h*32 + l2)*68 + r*32 + k];
        heads[((size_t)h*ROWS + row0 + r)*KD + k] = acc * invs[r][h];
    }
}

// ---------------- K3: out-projection + residual + LN partials -------------
__global__ __launch_bounds__(256) void outproj_kernel(
    const float* __restrict__ heads, const float* __restrict__ Wot,
    const float* __restrict__ h32, float* __restrict__ outp,
    float* __restrict__ ps, float* __restrict__ pq)
{
    const int gid = blockIdx.x * 256 + threadIdx.x;
    const int row = gid >> 7, e = gid & 127;
    float acc = h32[gid];
    #pragma unroll
    for (int h = 0; h < HN; h++) {
        const float4* hp = reinterpret_cast<const float4*>(heads + ((size_t)h*ROWS + row)*KD);
        const float4* wp = reinterpret_cast<const float4*>(Wot + (size_t)e*EMB + h*KD);
        #pragma unroll
        for (int i = 0; i < 8; i++) {
            float4 a = hp[i], w = wp[i];
            acc += a.x*w.x + a.y*w.y + a.z*w.z + a.w*w.w;
        }
    }
    outp[gid] = acc;
    float s = acc, q = acc * acc;
    #pragma unroll
    for (int off = 32; off >= 1; off >>= 1) { s += __shfl_xor(s, off); q += __shfl_xor(q, off); }
    __shared__ float ls[4], lq[4];
    if ((threadIdx.x & 63) == 0) { ls[threadIdx.x >> 6] = s; lq[threadIdx.x >> 6] = q; }
    __syncthreads();
    if (threadIdx.x == 0) {
        ps[blockIdx.x] = ls[0] + ls[1] + ls[2] + ls[3];
        pq[blockIdx.x] = lq[0] + lq[1] + lq[2] + lq[3];
    }
}

// ---------------- K4/K7: finalize LN stats per batch ----------------------
__global__ __launch_bounds__(256) void stats_kernel(
    const float* __restrict__ ps, const float* __restrict__ pq,
    float* __restrict__ stats, int per_b, float M)
{
    int b = blockIdx.x, t = threadIdx.x;
    float s = 0.f, q = 0.f;
    for (int i = t; i < per_b; i += 256) { s += ps[b * per_b + i]; q += pq[b * per_b + i]; }
    #pragma unroll
    for (int off = 32; off >= 1; off >>= 1) { s += __shfl_xor(s, off); q += __shfl_xor(q, off); }
    __shared__ float ls[4], lq[4];
    if ((t & 63) == 0) { ls[t >> 6] = s; lq[t >> 6] = q; }
    __syncthreads();
    if (t == 0) {
        s = ls[0] + ls[1] + ls[2] + ls[3];
        q = lq[0] + lq[1] + lq[2] + lq[3];
        float mean = s / M;
        float var = (q - s * s / M) / (M - 1.0f);
        stats[2 * b] = mean;
        stats[2 * b + 1] = 1.0f / sqrtf(var + EPS);
    }
}

// ---------------- K6: LN1-apply + FF1+relu+FF2+residual + LN partials -----
__global__ __launch_bounds__(256) void ff_kernel(
    const float* __restrict__ outp, const float* __restrict__ stats,
    const float* __restrict__ W1t, const float* __restrict__ W2t,
    float* __restrict__ outp2, float* __restrict__ ps, float* __restrict__ pq)
{
    __shared__ float xr[4][EMB];
    __shared__ float hid[4][FFH];
    __shared__ float rs[4], rq[4];
    const int t = threadIdx.x;
    const int row0 = blockIdx.x * 4;
    const int b = row0 >> 10;
    const float mean = stats[2*b], rstd = stats[2*b+1];

    #pragma unroll
    for (int i = 0; i < 2; i++) {
        int idx = t + 256*i;
        xr[idx >> 7][idx & 127] = (outp[(size_t)row0*EMB + idx] - mean) * rstd;
    }
    __syncthreads();

    {   // FF1: thread t owns hidden f = {t, t+256} for all 4 rows
        const float4* w0 = reinterpret_cast<const float4*>(W1t + (size_t)t * EMB);
        const float4* w1 = reinterpret_cast<const float4*>(W1t + (size_t)(t + 256) * EMB);
        float a[2][4] = {};
        #pragma unroll 8
        for (int i = 0; i < 32; i++) {
            float4 wa = w0[i], wb = w1[i];
            #pragma unroll
            for (int r = 0; r < 4; r++) {
                float4 x = *reinterpret_cast<const float4*>(&xr[r][i*4]);
                a[0][r] += wa.x*x.x + wa.y*x.y + wa.z*x.z + wa.w*x.w;
                a[1][r] += wb.x*x.x + wb.y*x.y + wb.z*x.z + wb.w*x.w;
            }
        }
        #pragma unroll
        for (int r = 0; r < 4; r++) {
            hid[r][t]       = fmaxf(a[0][r], 0.f);
            hid[r][t + 256] = fmaxf(a[1][r], 0.f);
        }
    }
    __syncthreads();

    // FF2: thread pair (e, half) splits the f-sum; all 4 rows share W row
    const int e = t >> 1, half = t & 1;
    float acc[4] = {};
    {
        const float4* wvp = reinterpret_cast<const float4*>(W2t + (size_t)e*FFH + half*256);
        #pragma unroll 8
        for (int i = 0; i < 64; i++) {
            float4 w = wvp[i];
            int fb = half*256 + i*4;
            #pragma unroll
            for (int r = 0; r < 4; r++) {
                float4 h4 = *reinterpret_cast<const float4*>(&hid[r][fb]);
                acc[r] += w.x*h4.x + w.y*h4.y + w.z*h4.z + w.w*h4.w;
            }
        }
    }
    #pragma unroll
    for (int r = 0; r < 4; r++) acc[r] += __shfl_xor(acc[r], 1);
    float s = 0.f, q = 0.f;
    if (half == 0) {
        #pragma unroll
        for (int r = 0; r < 4; r++) {
            float v = acc[r] + xr[r][e];
            outp2[(size_t)(row0 + r)*EMB + e] = v;
            s += v; q += v * v;
        }
    }
    #pragma unroll
    for (int off = 32; off >= 1; off >>= 1) { s += __shfl_xor(s, off); q += __shfl_xor(q, off); }
    if ((t & 63) == 0) { rs[t >> 6] = s; rq[t >> 6] = q; }
    __syncthreads();
    if (t == 0) {
        ps[blockIdx.x] = rs[0] + rs[1] + rs[2] + rs[3];
        pq[blockIdx.x] = rq[0] + rq[1] + rq[2] + rq[3];
    }
}

// ---------------- K8: apply LN2 -> float out ------------------------------
__global__ __launch_bounds__(256) void final_kernel(
    const float* __restrict__ in, const float* __restrict__ stats, float* __restrict__ out)
{
    int gid = blockIdx.x * 256 + threadIdx.x;
    int b = gid >> 17;
    out[gid] = (in[gid] - stats[2 * b]) * stats[2 * b + 1];
}

// ---------------- K9: input2 passthrough -> float out ---------------------
__global__ __launch_bounds__(256) void copy2_kernel(
    const void* __restrict__ in, uint4* __restrict__ out, const int* __restrict__ flags)
{
    const int f_2 = flags[1];
    size_t gid = (size_t)blockIdx.x * 256 + threadIdx.x;
    if (f_2) {
        out[gid] = ((const uint4*)in)[gid];
    } else {
        const bf16* p = (const bf16*)in + gid * 4;
        float4 v = { b2f(p[0]), b2f(p[1]), b2f(p[2]), b2f(p[3]) };
        out[gid] = *(const uint4*)&v;
    }
}

extern "C" void kernel_launch(void* const* d_in, const int* in_sizes, int n_in,
                              void* d_out, int out_size, void* d_ws, size_t ws_size,
                              hipStream_t stream)
{
    const void* input1 = d_in[0];
    const void* input2 = d_in[1];
    const void* Wq  = d_in[2];
    const void* Wk  = d_in[3];
    const void* Wv  = d_in[4];
    const void* Wo  = d_in[5];
    const void* Ws1 = d_in[6];
    const void* bs1 = d_in[7];
    const void* Ws2 = d_in[8];
    const void* bs2 = d_in[9];
    const void* Wf1 = d_in[10];
    const void* Wf2 = d_in[11];

    float* out1 = (float*)d_out;                       // [ROWS*EMB] f32
    float* out2 = (float*)d_out + (size_t)ROWS * EMB;  // input2 passthrough (written LAST)

    // Scratch inside the out2 region (~29 MiB used of 128 MiB); all consumers
    // finish before copy2 overwrites it.
    char* sb = (char*)out2;
    float* Q32   = (float*)(sb);                       // 4 MB
    float* Kt32  = (float*)(sb + (4u  << 20));         // 4 MB
    float* Vt32  = (float*)(sb + (8u  << 20));         // 4 MB
    float* heads = (float*)(sb + (12u << 20));         // 4 MB
    float* outp  = (float*)(sb + (16u << 20));         // 4 MB
    float* outp2 = (float*)(sb + (20u << 20));         // 4 MB
    float* h32   = (float*)(sb + (24u << 20));         // 4 MB
    float* Wt    = (float*)(sb + (28u << 20));                 // 192 KB
    float* Wot   = (float*)(sb + (28u << 20) + 0x30000);       // 64 KB
    float* W1t   = (float*)(sb + (28u << 20) + 0x40000);       // 256 KB
    float* W2t   = (float*)(sb + (28u << 20) + 0x80000);       // 256 KB
    float* mlp32 = (float*)(sb + (28u << 20) + 0xC0000);       // 432 B
    float* ps    = (float*)(sb + (28u << 20) + 0xC1000);       // 16 KB
    float* pq    = (float*)(sb + (28u << 20) + 0xC5000);       // 16 KB
    float* stats = (float*)(sb + (28u << 20) + 0xC9000);
    float* stats2= (float*)(sb + (28u << 20) + 0xC9100);
    int*   flags = (int*)  (sb + (28u << 20) + 0xC9200);

    const float M = (float)(SEQ * EMB);                // 131072 per batch

    hipLaunchKernelGGL(detect_kernel, dim3(9), dim3(256), 0, stream,
                       (const unsigned int*)input1, (const unsigned int*)input2,
                       (const unsigned int*)Wq, (const unsigned int*)Wk,
                       (const unsigned int*)Wv, (const unsigned int*)Wo,
                       (const unsigned int*)Ws1, (const unsigned int*)bs1,
                       (const unsigned int*)Ws2, (const unsigned int*)bs2,
                       (const unsigned int*)Wf1, (const unsigned int*)Wf2, flags);
    hipLaunchKernelGGL(convert_kernel, dim3(1793), dim3(256), 0, stream,
                       input1, Wq, Wk, Wv, Wo, Ws1, bs1, Ws2, bs2, Wf1, Wf2,
                       h32, Wt, Wot, W1t, W2t, mlp32, flags);
    hipLaunchKernelGGL(qkv_kernel, dim3(768), dim3(256), 0, stream,
                       h32, Wt, Q32, Kt32, Vt32);
    hipLaunchKernelGGL(attn_kernel, dim3(ROWS / 2), dim3(256), 0, stream,
                       Q32, Kt32, Vt32, input2, mlp32, heads, flags);
    hipLaunchKernelGGL(outproj_kernel, dim3(ROWS * EMB / 256), dim3(256), 0, stream,
                       heads, Wot, h32, outp, ps, pq);
    hipLaunchKernelGGL(stats_kernel, dim3(NB), dim3(256), 0, stream,
                       ps, pq, stats, 512, M);
    hipLaunchKernelGGL(ff_kernel, dim3(ROWS / 4), dim3(256), 0, stream,
                       outp, stats, W1t, W2t, outp2, ps, pq);
    hipLaunchKernelGGL(stats_kernel, dim3(NB), dim3(256), 0, stream,
                       ps, pq, stats2, 256, M);
    hipLaunchKernelGGL(final_kernel, dim3(ROWS * EMB / 256), dim3(256), 0, stream,
                       outp2, stats2, out1);
    hipLaunchKernelGGL(copy2_kernel, dim3(ROWS * SEQ * HN / 4 / 256), dim3(256), 0, stream,
                       input2, (uint4*)out2, flags);
}

// Round 6
// 774.559 us; speedup vs baseline: 1.4090x; 1.2680x over previous
//
#include <hip/hip_runtime.h>
#include <hip/hip_bf16.h>

typedef __hip_bfloat16 bf16;

static constexpr int HN  = 4;     // heads
static constexpr int NB  = 8;     // batch
static constexpr int SEQ = 1024;  // nodes
static constexpr int EMB = 128;
static constexpr int KD  = 32;
static constexpr int FFH = 512;
static constexpr int ROWS = NB * SEQ;       // 8192
static constexpr float EPS = 1e-5f;

__device__ __forceinline__ float b2f(bf16 x){ return __bfloat162float(x); }

// dtype-dispatched load: flag==1 -> buffer is float32, else bf16
__device__ __forceinline__ float ldx(const void* p, size_t i, int f32){
    return f32 ? ((const float*)p)[i] : b2f(((const bf16*)p)[i]);
}

// ---------------- K0: per-input dtype detector ----------------------------
__device__ __forceinline__ float probe_max(const unsigned int* w, int nwords, int t){
    float mx = 0.f;
    for (int i = t; i < nwords; i += 256) {
        float v = fabsf(__uint_as_float(w[i] << 16));
        if (!(v <= 1e4f)) v = 1e30f;
        mx = fmaxf(mx, v);
    }
    return mx;
}

// flags: 0=input1 1=input2 2=Wq 3=Wk 4=Wv 5=Wo 6=tinyMLP 7=Wff1 8=Wff2
__global__ __launch_bounds__(256) void detect_kernel(
    const unsigned int* in1, const unsigned int* in2,
    const unsigned int* wq,  const unsigned int* wk, const unsigned int* wv,
    const unsigned int* wo,  const unsigned int* ws1, const unsigned int* bs1,
    const unsigned int* ws2, const unsigned int* bs2,
    const unsigned int* wf1, const unsigned int* wf2, int* __restrict__ flags)
{
    __shared__ float red[4];
    const int b = blockIdx.x, t = threadIdx.x;
    float mx = 0.f;
    if      (b == 0) mx = probe_max(in1, 4096, t);
    else if (b == 1) mx = probe_max(in2, 4096, t);
    else if (b == 2) mx = probe_max(wq, 4096, t);
    else if (b == 3) mx = probe_max(wk, 4096, t);
    else if (b == 4) mx = probe_max(wv, 4096, t);
    else if (b == 5) mx = probe_max(wo, 4096, t);
    else if (b == 6) {
        mx = fmaxf(probe_max(ws1, 32, t), probe_max(bs1, 4, t));
        mx = fmaxf(mx, fmaxf(probe_max(ws2, 16, t), probe_max(bs2, 2, t)));
    }
    else if (b == 7) mx = probe_max(wf1, 4096, t);
    else             mx = probe_max(wf2, 4096, t);

    #pragma unroll
    for (int off = 32; off >= 1; off >>= 1) mx = fmaxf(mx, __shfl_xor(mx, off));
    if ((t & 63) == 0) red[t >> 6] = mx;
    __syncthreads();
    if (t == 0) {
        mx = fmaxf(fmaxf(red[0], red[1]), fmaxf(red[2], red[3]));
        flags[b] = (mx > 1e4f) ? 1 : 0;
    }
}

// ---------------- K0b: resolve dtypes + transpose weights ONCE ------------
__global__ __launch_bounds__(256) void convert_kernel(
    const void* in1, const void* Wq, const void* Wk, const void* Wv, const void* Wo,
    const void* Ws1, const void* bs1, const void* Ws2, const void* bs2,
    const void* Wf1, const void* Wf2,
    float* __restrict__ h32, float* __restrict__ Wt, float* __restrict__ Wot,
    float* __restrict__ W1t, float* __restrict__ W2t, float* __restrict__ mlp32,
    const int* __restrict__ flags)
{
    int gid = blockIdx.x * 256 + threadIdx.x;
    if (gid < 262144) {                         // input1 -> f32, 4 elems/thread
        if (flags[0]) {
            ((float4*)h32)[gid] = ((const float4*)in1)[gid];
        } else {
            const bf16* p = (const bf16*)in1 + (size_t)gid * 4;
            h32[gid*4+0] = b2f(p[0]); h32[gid*4+1] = b2f(p[1]);
            h32[gid*4+2] = b2f(p[2]); h32[gid*4+3] = b2f(p[3]);
        }
        return;
    }
    int r = gid - 262144;
    if (r < 49152) {                            // Wt[mat][h][k][e] = W[h][e][k]
        int mat = r >> 14, q = r & 16383;
        int h = q >> 12, k = (q >> 7) & 31, e = q & 127;
        const void* W = (mat == 0) ? Wq : (mat == 1) ? Wk : Wv;
        Wt[r] = ldx(W, (size_t)(h*EMB + e)*KD + k, flags[2+mat]);
        return;
    }
    r -= 49152;
    if (r < 16384) {                            // Wot[e][hk] = Wo[hk][e]
        int e = r >> 7, hk = r & 127;
        Wot[r] = ldx(Wo, (size_t)hk*EMB + e, flags[5]);
        return;
    }
    r -= 16384;
    if (r < 65536) {                            // W1t[f][e] = Wf1[e][f]
        int f = r >> 7, e = r & 127;
        W1t[r] = ldx(Wf1, (size_t)e*FFH + f, flags[7]);
        return;
    }
    r -= 65536;
    if (r < 65536) {                            // W2t[e][f] = Wf2[f][e]
        int e = r >> 9, f = r & 511;
        W2t[r] = ldx(Wf2, (size_t)f*EMB + e, flags[8]);
        return;
    }
    r -= 65536;
    if (r < 108) {
        const int fm = flags[6];
        float v;
        if (r < 64)       { int j = r >> 3, i = r & 7; v = ldx(Ws1, i*8 + j, fm); }
        else if (r < 72)  v = ldx(bs1, r - 64, fm);
        else if (r < 104) v = ldx(Ws2, r - 72, fm);    // w2[j][c] row-major kept
        else              v = ldx(bs2, r - 104, fm);
        mlp32[r] = v;
    }
}

// ---------------- K1: QKV projection, LDS-tiled GEMM ----------------------
// Outputs (all f32): Q32[h][row][k], Kt32[h][b][k][n], Vt32[h][b][k][n]
__global__ __launch_bounds__(256) void qkv_kernel(
    const float* __restrict__ h32, const float* __restrict__ Wt,
    float* __restrict__ Q32, float* __restrict__ Kt32, float* __restrict__ Vt32)
{
    __shared__ float hl[128 * 132];
    const int t   = threadIdx.x;
    const int bid = blockIdx.x;
    const int mat = bid >> 8;                   // 768 = 3 * 4 * 64
    const int hh  = (bid >> 6) & 3;
    const int rt  = bid & 63;
    const int row0 = rt * 128;

    #pragma unroll
    for (int i = 0; i < 16; i++) {
        int idx = t + 256 * i;
        int r  = idx >> 5;
        int e4 = (idx & 31) * 4;
        float4 v = *reinterpret_cast<const float4*>(h32 + (size_t)(row0 + r) * EMB + e4);
        *reinterpret_cast<float4*>(&hl[r * 132 + e4]) = v;
    }
    __syncthreads();

    const int rq = t >> 3;
    const int kq = t & 7;
    const float* wbase = Wt + ((size_t)(mat * HN + hh) * KD + kq * 4) * EMB;
    float acc[4][4] = {};
    #pragma unroll 4
    for (int eq = 0; eq < 32; eq++) {
        float4 a0 = *reinterpret_cast<const float4*>(&hl[(rq*4+0)*132 + eq*4]);
        float4 a1 = *reinterpret_cast<const float4*>(&hl[(rq*4+1)*132 + eq*4]);
        float4 a2 = *reinterpret_cast<const float4*>(&hl[(rq*4+2)*132 + eq*4]);
        float4 a3 = *reinterpret_cast<const float4*>(&hl[(rq*4+3)*132 + eq*4]);
        float4 w0 = *reinterpret_cast<const float4*>(wbase + 0*EMB + eq*4);
        float4 w1 = *reinterpret_cast<const float4*>(wbase + 1*EMB + eq*4);
        float4 w2 = *reinterpret_cast<const float4*>(wbase + 2*EMB + eq*4);
        float4 w3 = *reinterpret_cast<const float4*>(wbase + 3*EMB + eq*4);
        #pragma unroll
        for (int kk = 0; kk < 4; kk++) {
            float4 w = (kk==0)?w0:(kk==1)?w1:(kk==2)?w2:w3;
            acc[0][kk] += a0.x*w.x + a0.y*w.y + a0.z*w.z + a0.w*w.w;
            acc[1][kk] += a1.x*w.x + a1.y*w.y + a1.z*w.z + a1.w*w.w;
            acc[2][kk] += a2.x*w.x + a2.y*w.y + a2.z*w.z + a2.w*w.w;
            acc[3][kk] += a3.x*w.x + a3.y*w.y + a3.z*w.z + a3.w*w.w;
        }
    }

    if (mat == 0) {
        #pragma unroll
        for (int r = 0; r < 4; r++) {
            float4 v = { acc[r][0], acc[r][1], acc[r][2], acc[r][3] };
            *reinterpret_cast<float4*>(Q32 + ((size_t)hh*ROWS + row0 + rq*4 + r)*KD + kq*4) = v;
        }
    } else {
        float* out = (mat == 1) ? Kt32 : Vt32;
        int bb = row0 >> 10;
        int n0 = (row0 & 1023) + rq * 4;
        #pragma unroll
        for (int kk = 0; kk < 4; kk++) {
            float4 v = { acc[0][kk], acc[1][kk], acc[2][kk], acc[3][kk] };
            *reinterpret_cast<float4*>(out + ((size_t)(hh*NB + bb)*KD + kq*4 + kk)*SEQ + n0) = v;
        }
    }
}

// ---------------- K2: fused attention, 2 rows per block -------------------
// LDS plane map: scores s[h][r] -> plane h*2+r; logits z[c][r] -> plane c*2+r
// (row pass r reads planes {h*2+r}, writes {c*2+r} - same set, thread-private
//  m-window -> no hazard, and row (1-r) planes untouched).
// Register budget kept ~130: per-row MLP, k-halved PV (unroll 1 on halves).
__global__ __launch_bounds__(256, 3) void attn_kernel(
    const float* __restrict__ Q32, const float* __restrict__ Kt32,
    const float* __restrict__ Vt32, const void* __restrict__ in2,
    const float* __restrict__ mlp, float* __restrict__ heads,
    const int* __restrict__ flags)
{
    __shared__ float sz[8704];          // 8 planes [1024] ∪ red[4][32][68]
    __shared__ float qld[HN][2][KD];
    __shared__ float wm[108];
    __shared__ float invs[2][HN];

    const int t = threadIdx.x;
    // XCD swizzle: contiguous 512-block chunk (one batch) per XCD.
    const int wg   = (blockIdx.x & 7) * 512 + (blockIdx.x >> 3);
    const int row0 = wg * 2;
    const int b    = row0 >> 10;
    const int n0   = row0 & (SEQ - 1);
    const int m0   = t * 4;
    const int f2   = flags[1];
    const int w    = t >> 6, l = t & 63;

    { int h = t >> 6, r = (t >> 5) & 1, k = t & 31;
      qld[h][r][k] = Q32[((size_t)h*ROWS + row0 + r)*KD + k]; }
    if (t < 108) wm[t] = mlp[t];

    // in2 prefetch (regs) - issued early, consumed in Phase 2
    float4 i2v[2][4];
    #pragma unroll
    for (int r = 0; r < 2; r++) {
        #pragma unroll
        for (int c = 0; c < 4; c++) {
            size_t base = ((size_t)(c*NB + b)*SEQ + (n0 + r))*SEQ + m0;
            if (f2) {
                i2v[r][c] = *reinterpret_cast<const float4*>((const float*)in2 + base);
            } else {
                const ushort* p = (const ushort*)in2 + base;
                ushort4 u = *reinterpret_cast<const ushort4*>(p);
                i2v[r][c] = make_float4(
                    __uint_as_float((unsigned)u.x << 16), __uint_as_float((unsigned)u.y << 16),
                    __uint_as_float((unsigned)u.z << 16), __uint_as_float((unsigned)u.w << 16));
            }
        }
    }
    __syncthreads();

    // ---- Phase 1: wave w = head w; both rows; float4 K loads ----
    {
        float q0[KD], q1[KD];
        const float4* qp0 = reinterpret_cast<const float4*>(&qld[w][0][0]);
        const float4* qp1 = reinterpret_cast<const float4*>(&qld[w][1][0]);
        #pragma unroll
        for (int i = 0; i < 8; i++) {
            float4 a = qp0[i], c = qp1[i];
            q0[4*i+0]=a.x; q0[4*i+1]=a.y; q0[4*i+2]=a.z; q0[4*i+3]=a.w;
            q1[4*i+0]=c.x; q1[4*i+1]=c.y; q1[4*i+2]=c.z; q1[4*i+3]=c.w;
        }
        const float* kb = Kt32 + ((size_t)(w*NB + b)*KD)*SEQ;
        #pragma unroll 2
        for (int mc = 0; mc < 4; mc++) {
            const int m = mc*256 + l*4;
            float a0x=0.f,a0y=0.f,a0z=0.f,a0w=0.f;
            float a1x=0.f,a1y=0.f,a1z=0.f,a1w=0.f;
            #pragma unroll
            for (int k = 0; k < KD; k++) {
                float4 kv = *reinterpret_cast<const float4*>(kb + (size_t)k*SEQ + m);
                a0x += q0[k]*kv.x; a0y += q0[k]*kv.y; a0z += q0[k]*kv.z; a0w += q0[k]*kv.w;
                a1x += q1[k]*kv.x; a1y += q1[k]*kv.y; a1z += q1[k]*kv.z; a1w += q1[k]*kv.w;
            }
            *reinterpret_cast<float4*>(&sz[(w*2+0)*SEQ + m]) = make_float4(a0x,a0y,a0z,a0w);
            *reinterpret_cast<float4*>(&sz[(w*2+1)*SEQ + m]) = make_float4(a1x,a1y,a1z,a1w);
        }
    }
    __syncthreads();

    // ---- Phase 2: tiny MLP, per-row pass (halves register pressure) ----
    #pragma unroll 1
    for (int r = 0; r < 2; r++) {
        float xx[4][8];                 // [m][channel]
        #pragma unroll
        for (int h = 0; h < HN; h++) {
            float4 s4 = *reinterpret_cast<const float4*>(&sz[(h*2+r)*SEQ + m0]);
            xx[0][h]=s4.x; xx[1][h]=s4.y; xx[2][h]=s4.z; xx[3][h]=s4.w;
        }
        #pragma unroll
        for (int c = 0; c < 4; c++) {
            float4 v = i2v[r][c];
            xx[0][4+c]=v.x; xx[1][4+c]=v.y; xx[2][4+c]=v.z; xx[3][4+c]=v.w;
        }
        float zc[4][4];
        #pragma unroll
        for (int m = 0; m < 4; m++)
            #pragma unroll
            for (int c = 0; c < 4; c++) zc[m][c] = wm[104 + c];
        #pragma unroll
        for (int j = 0; j < 8; j++) {
            float4 wa = *reinterpret_cast<const float4*>(&wm[j*8]);
            float4 wb = *reinterpret_cast<const float4*>(&wm[j*8+4]);
            float w1j[8] = {wa.x,wa.y,wa.z,wa.w, wb.x,wb.y,wb.z,wb.w};
            float b1j = wm[64 + j];
            float4 w2v = *reinterpret_cast<const float4*>(&wm[72 + j*4]);
            #pragma unroll
            for (int m = 0; m < 4; m++) {
                float y = b1j;
                #pragma unroll
                for (int i = 0; i < 8; i++) y += xx[m][i] * w1j[i];
                y = fmaxf(y, 0.f);
                zc[m][0] += y * w2v.x; zc[m][1] += y * w2v.y;
                zc[m][2] += y * w2v.z; zc[m][3] += y * w2v.w;
            }
        }
        #pragma unroll
        for (int c = 0; c < 4; c++)
            *reinterpret_cast<float4*>(&sz[(c*2 + r)*SEQ + m0]) =
                make_float4(zc[0][c], zc[1][c], zc[2][c], zc[3][c]);
    }
    __syncthreads();

    // ---- Phase 3: wave w = head w softmax; lane l owns m in {4l+256i} ----
    float p0[16], p1[16];
    {
        #pragma unroll
        for (int i = 0; i < 4; i++) {
            float4 a = *reinterpret_cast<const float4*>(&sz[(w*2+0)*SEQ + i*256 + l*4]);
            float4 c = *reinterpret_cast<const float4*>(&sz[(w*2+1)*SEQ + i*256 + l*4]);
            p0[4*i+0]=a.x; p0[4*i+1]=a.y; p0[4*i+2]=a.z; p0[4*i+3]=a.w;
            p1[4*i+0]=c.x; p1[4*i+1]=c.y; p1[4*i+2]=c.z; p1[4*i+3]=c.w;
        }
        float mx0 = -1e30f, mx1 = -1e30f;
        #pragma unroll
        for (int i = 0; i < 16; i++) { mx0 = fmaxf(mx0, p0[i]); mx1 = fmaxf(mx1, p1[i]); }
        #pragma unroll
        for (int off = 32; off >= 1; off >>= 1) {
            mx0 = fmaxf(mx0, __shfl_xor(mx0, off));
            mx1 = fmaxf(mx1, __shfl_xor(mx1, off));
        }
        float s0 = 0.f, s1 = 0.f;
        #pragma unroll
        for (int i = 0; i < 16; i++) {
            p0[i] = __expf(p0[i] - mx0); s0 += p0[i];
            p1[i] = __expf(p1[i] - mx1); s1 += p1[i];
        }
        #pragma unroll
        for (int off = 32; off >= 1; off >>= 1) { s0 += __shfl_xor(s0, off); s1 += __shfl_xor(s1, off); }
        if (l == 0) { invs[0][w] = 1.f / s0; invs[1][w] = 1.f / s1; }
    }
    __syncthreads();                     // z consumed -> sz reusable as red

    // ---- Phase 4: PV in two k-halves (16 accs/row, NOT 32) ----
    #pragma unroll 1
    for (int kh = 0; kh < 2; kh++) {
        float o0[16], o1[16];
        #pragma unroll
        for (int i = 0; i < 16; i++) { o0[i] = 0.f; o1[i] = 0.f; }
        const float* vb = Vt32 + ((size_t)(w*NB + b)*KD + kh*16)*SEQ + l*4;
        #pragma unroll
        for (int k16 = 0; k16 < 16; k16++) {
            const float* vk = vb + (size_t)k16*SEQ;
            float4 v0 = *reinterpret_cast<const float4*>(vk + 0*256);
            float4 v1 = *reinterpret_cast<const float4*>(vk + 1*256);
            float4 v2 = *reinterpret_cast<const float4*>(vk + 2*256);
            float4 v3 = *reinterpret_cast<const float4*>(vk + 3*256);
            o0[k16] = p0[ 0]*v0.x + p0[ 1]*v0.y + p0[ 2]*v0.z + p0[ 3]*v0.w
                    + p0[ 4]*v1.x + p0[ 5]*v1.y + p0[ 6]*v1.z + p0[ 7]*v1.w
                    + p0[ 8]*v2.x + p0[ 9]*v2.y + p0[10]*v2.z + p0[11]*v2.w
                    + p0[12]*v3.x + p0[13]*v3.y + p0[14]*v3.z + p0[15]*v3.w;
            o1[k16] = p1[ 0]*v0.x + p1[ 1]*v0.y + p1[ 2]*v0.z + p1[ 3]*v0.w
                    + p1[ 4]*v1.x + p1[ 5]*v1.y + p1[ 6]*v1.z + p1[ 7]*v1.w
                    + p1[ 8]*v2.x + p1[ 9]*v2.y + p1[10]*v2.z + p1[11]*v2.w
                    + p1[12]*v3.x + p1[13]*v3.y + p1[14]*v3.z + p1[15]*v3.w;
        }
        #pragma unroll
        for (int i = 0; i < 16; i++) { o0[i] += __shfl_xor(o0[i], 32); o1[i] += __shfl_xor(o1[i], 32); }
        if (l < 32) {
            float* rr = &sz[(w*32 + l)*68 + kh*16];
            #pragma unroll
            for (int i = 0; i < 4; i++) {
                *reinterpret_cast<float4*>(rr + i*4)      = make_float4(o0[4*i], o0[4*i+1], o0[4*i+2], o0[4*i+3]);
                *reinterpret_cast<float4*>(rr + 32 + i*4) = make_float4(o1[4*i], o1[4*i+1], o1[4*i+2], o1[4*i+3]);
            }
        }
    }
    __syncthreads();
    {
        int r = t >> 7, h = (t >> 5) & 3, k = t & 31;
        float acc = 0.f;
        #pragma unroll 8
        for (int l2 = 0; l2 < 32; l2++) acc += sz[(h*32 + l2)*68 + r*32 + k];
        heads[((size_t)h*ROWS + row0 + r)*KD + k] = acc * invs[r][h];
    }
}

// ---------------- K3: out-projection + residual + LN partials -------------
__global__ __launch_bounds__(256) void outproj_kernel(
    const float* __restrict__ heads, const float* __restrict__ Wot,
    const float* __restrict__ h32, float* __restrict__ outp,
    float* __restrict__ ps, float* __restrict__ pq)
{
    const int gid = blockIdx.x * 256 + threadIdx.x;
    const int row = gid >> 7, e = gid & 127;
    float acc = h32[gid];
    #pragma unroll
    for (int h = 0; h < HN; h++) {
        const float4* hp = reinterpret_cast<const float4*>(heads + ((size_t)h*ROWS + row)*KD);
        const float4* wp = reinterpret_cast<const float4*>(Wot + (size_t)e*EMB + h*KD);
        #pragma unroll
        for (int i = 0; i < 8; i++) {
            float4 a = hp[i], w = wp[i];
            acc += a.x*w.x + a.y*w.y + a.z*w.z + a.w*w.w;
        }
    }
    outp[gid] = acc;
    float s = acc, q = acc * acc;
    #pragma unroll
    for (int off = 32; off >= 1; off >>= 1) { s += __shfl_xor(s, off); q += __shfl_xor(q, off); }
    __shared__ float ls[4], lq[4];
    if ((threadIdx.x & 63) == 0) { ls[threadIdx.x >> 6] = s; lq[threadIdx.x >> 6] = q; }
    __syncthreads();
    if (threadIdx.x == 0) {
        ps[blockIdx.x] = ls[0] + ls[1] + ls[2] + ls[3];
        pq[blockIdx.x] = lq[0] + lq[1] + lq[2] + lq[3];
    }
}

// ---------------- K4/K7: finalize LN stats per batch ----------------------
__global__ __launch_bounds__(256) void stats_kernel(
    const float* __restrict__ ps, const float* __restrict__ pq,
    float* __restrict__ stats, int per_b, float M)
{
    int b = blockIdx.x, t = threadIdx.x;
    float s = 0.f, q = 0.f;
    for (int i = t; i < per_b; i += 256) { s += ps[b * per_b + i]; q += pq[b * per_b + i]; }
    #pragma unroll
    for (int off = 32; off >= 1; off >>= 1) { s += __shfl_xor(s, off); q += __shfl_xor(q, off); }
    __shared__ float ls[4], lq[4];
    if ((t & 63) == 0) { ls[t >> 6] = s; lq[t >> 6] = q; }
    __syncthreads();
    if (t == 0) {
        s = ls[0] + ls[1] + ls[2] + ls[3];
        q = lq[0] + lq[1] + lq[2] + lq[3];
        float mean = s / M;
        float var = (q - s * s / M) / (M - 1.0f);
        stats[2 * b] = mean;
        stats[2 * b + 1] = 1.0f / sqrtf(var + EPS);
    }
}

// ---------------- K6: LN1-apply + FF1+relu+FF2+residual + LN partials -----
// 8 rows per block (halves W1/W2 L2 re-read traffic vs 4 rows)
__global__ __launch_bounds__(256) void ff_kernel(
    const float* __restrict__ outp, const float* __restrict__ stats,
    const float* __restrict__ W1t, const float* __restrict__ W2t,
    float* __restrict__ outp2, float* __restrict__ ps, float* __restrict__ pq)
{
    __shared__ float xr[8][EMB];        // 4 KB
    __shared__ float hid[8][FFH];       // 16 KB
    __shared__ float rs[4], rq[4];
    const int t = threadIdx.x;
    const int row0 = blockIdx.x * 8;
    const int b = row0 >> 10;
    const float mean = stats[2*b], rstd = stats[2*b+1];

    {   // load 8x128 via float4, apply LN1
        float4 x4 = *reinterpret_cast<const float4*>(outp + (size_t)row0*EMB + t*4);
        int rr = t >> 5, cc = (t*4) & 127;
        xr[rr][cc+0] = (x4.x - mean)*rstd; xr[rr][cc+1] = (x4.y - mean)*rstd;
        xr[rr][cc+2] = (x4.z - mean)*rstd; xr[rr][cc+3] = (x4.w - mean)*rstd;
    }
    __syncthreads();

    {   // FF1: thread t owns hidden f = {t, t+256} for all 8 rows
        const float4* w0 = reinterpret_cast<const float4*>(W1t + (size_t)t * EMB);
        const float4* w1 = reinterpret_cast<const float4*>(W1t + (size_t)(t + 256) * EMB);
        float a[2][8] = {};
        #pragma unroll 8
        for (int i = 0; i < 32; i++) {
            float4 wa = w0[i], wb = w1[i];
            #pragma unroll
            for (int r = 0; r < 8; r++) {
                float4 x = *reinterpret_cast<const float4*>(&xr[r][i*4]);
                a[0][r] += wa.x*x.x + wa.y*x.y + wa.z*x.z + wa.w*x.w;
                a[1][r] += wb.x*x.x + wb.y*x.y + wb.z*x.z + wb.w*x.w;
            }
        }
        #pragma unroll
        for (int r = 0; r < 8; r++) {
            hid[r][t]       = fmaxf(a[0][r], 0.f);
            hid[r][t + 256] = fmaxf(a[1][r], 0.f);
        }
    }
    __syncthreads();

    // FF2: thread pair (e, half) splits the f-sum; all 8 rows share W row
    const int e = t >> 1, half = t & 1;
    float acc[8] = {};
    {
        const float4* wvp = reinterpret_cast<const float4*>(W2t + (size_t)e*FFH + half*256);
        #pragma unroll 8
        for (int i = 0; i < 64; i++) {
            float4 w = wvp[i];
            int fb = half*256 + i*4;
            #pragma unroll
            for (int r = 0; r < 8; r++) {
                float4 h4 = *reinterpret_cast<const float4*>(&hid[r][fb]);
                acc[r] += w.x*h4.x + w.y*h4.y + w.z*h4.z + w.w*h4.w;
            }
        }
    }
    #pragma unroll
    for (int r = 0; r < 8; r++) acc[r] += __shfl_xor(acc[r], 1);
    float s = 0.f, q = 0.f;
    if (half == 0) {
        #pragma unroll
        for (int r = 0; r < 8; r++) {
            float v = acc[r] + xr[r][e];
            outp2[(size_t)(row0 + r)*EMB + e] = v;
            s += v; q += v * v;
        }
    }
    #pragma unroll
    for (int off = 32; off >= 1; off >>= 1) { s += __shfl_xor(s, off); q += __shfl_xor(q, off); }
    if ((t & 63) == 0) { rs[t >> 6] = s; rq[t >> 6] = q; }
    __syncthreads();
    if (t == 0) {
        ps[blockIdx.x] = rs[0] + rs[1] + rs[2] + rs[3];
        pq[blockIdx.x] = rq[0] + rq[1] + rq[2] + rq[3];
    }
}

// ---------------- K8: apply LN2 -> float out ------------------------------
__global__ __launch_bounds__(256) void final_kernel(
    const float* __restrict__ in, const float* __restrict__ stats, float* __restrict__ out)
{
    int gid = blockIdx.x * 256 + threadIdx.x;
    int b = gid >> 17;
    out[gid] = (in[gid] - stats[2 * b]) * stats[2 * b + 1];
}

// ---------------- K9: input2 passthrough -> float out ---------------------
__global__ __launch_bounds__(256) void copy2_kernel(
    const void* __restrict__ in, uint4* __restrict__ out, const int* __restrict__ flags)
{
    const int f_2 = flags[1];
    size_t gid = (size_t)blockIdx.x * 256 + threadIdx.x;
    if (f_2) {
        out[gid] = ((const uint4*)in)[gid];
    } else {
        const bf16* p = (const bf16*)in + gid * 4;
        float4 v = { b2f(p[0]), b2f(p[1]), b2f(p[2]), b2f(p[3]) };
        out[gid] = *(const uint4*)&v;
    }
}

extern "C" void kernel_launch(void* const* d_in, const int* in_sizes, int n_in,
                              void* d_out, int out_size, void* d_ws, size_t ws_size,
                              hipStream_t stream)
{
    const void* input1 = d_in[0];
    const void* input2 = d_in[1];
    const void* Wq  = d_in[2];
    const void* Wk  = d_in[3];
    const void* Wv  = d_in[4];
    const void* Wo  = d_in[5];
    const void* Ws1 = d_in[6];
    const void* bs1 = d_in[7];
    const void* Ws2 = d_in[8];
    const void* bs2 = d_in[9];
    const void* Wf1 = d_in[10];
    const void* Wf2 = d_in[11];

    float* out1 = (float*)d_out;                       // [ROWS*EMB] f32
    float* out2 = (float*)d_out + (size_t)ROWS * EMB;  // input2 passthrough (written LAST)

    char* sb = (char*)out2;
    float* Q32   = (float*)(sb);                       // 4 MB
    float* Kt32  = (float*)(sb + (4u  << 20));         // 4 MB
    float* Vt32  = (float*)(sb + (8u  << 20));         // 4 MB
    float* heads = (float*)(sb + (12u << 20));         // 4 MB
    float* outp  = (float*)(sb + (16u << 20));         // 4 MB
    float* outp2 = (float*)(sb + (20u << 20));         // 4 MB
    float* h32   = (float*)(sb + (24u << 20));         // 4 MB
    float* Wt    = (float*)(sb + (28u << 20));                 // 192 KB
    float* Wot   = (float*)(sb + (28u << 20) + 0x30000);       // 64 KB
    float* W1t   = (float*)(sb + (28u << 20) + 0x40000);       // 256 KB
    float* W2t   = (float*)(sb + (28u << 20) + 0x80000);       // 256 KB
    float* mlp32 = (float*)(sb + (28u << 20) + 0xC0000);       // 432 B
    float* ps    = (float*)(sb + (28u << 20) + 0xC1000);       // 16 KB
    float* pq    = (float*)(sb + (28u << 20) + 0xC5000);       // 16 KB
    float* stats = (float*)(sb + (28u << 20) + 0xC9000);
    float* stats2= (float*)(sb + (28u << 20) + 0xC9100);
    int*   flags = (int*)  (sb + (28u << 20) + 0xC9200);

    const float M = (float)(SEQ * EMB);                // 131072 per batch

    hipLaunchKernelGGL(detect_kernel, dim3(9), dim3(256), 0, stream,
                       (const unsigned int*)input1, (const unsigned int*)input2,
                       (const unsigned int*)Wq, (const unsigned int*)Wk,
                       (const unsigned int*)Wv, (const unsigned int*)Wo,
                       (const unsigned int*)Ws1, (const unsigned int*)bs1,
                       (const unsigned int*)Ws2, (const unsigned int*)bs2,
                       (const unsigned int*)Wf1, (const unsigned int*)Wf2, flags);
    hipLaunchKernelGGL(convert_kernel, dim3(1793), dim3(256), 0, stream,
                       input1, Wq, Wk, Wv, Wo, Ws1, bs1, Ws2, bs2, Wf1, Wf2,
                       h32, Wt, Wot, W1t, W2t, mlp32, flags);
    hipLaunchKernelGGL(qkv_kernel, dim3(768), dim3(256), 0, stream,
                       h32, Wt, Q32, Kt32, Vt32);
    hipLaunchKernelGGL(attn_kernel, dim3(ROWS / 2), dim3(256), 0, stream,
                       Q32, Kt32, Vt32, input2, mlp32, heads, flags);
    hipLaunchKernelGGL(outproj_kernel, dim3(ROWS * EMB / 256), dim3(256), 0, stream,
                       heads, Wot, h32, outp, ps, pq);
    hipLaunchKernelGGL(stats_kernel, dim3(NB), dim3(256), 0, stream,
                       ps, pq, stats, 512, M);
    hipLaunchKernelGGL(ff_kernel, dim3(ROWS / 8), dim3(256), 0, stream,
                       outp, stats, W1t, W2t, outp2, ps, pq);
    hipLaunchKernelGGL(stats_kernel, dim3(NB), dim3(256), 0, stream,
                       ps, pq, stats2, 128, M);
    hipLaunchKernelGGL(final_kernel, dim3(ROWS * EMB / 256), dim3(256), 0, stream,
                       outp2, stats2, out1);
    hipLaunchKernelGGL(copy2_kernel, dim3(ROWS * SEQ * HN / 4 / 256), dim3(256), 0, stream,
                       input2, (uint4*)out2, flags);
}